// Round 1
// baseline (650.663 us; speedup 1.0000x reference)
//
#include <hip/hip_runtime.h>
#include <math.h>

#define S_TOK 8192
#define DDIM 2048
#define HDIM 2048
#define NE 8
#define CAP 2048
#define NBATCH 4
#define TT 2048

typedef _Float16 f16;
typedef _Float16 f16x4 __attribute__((ext_vector_type(4)));
typedef _Float16 f16x8 __attribute__((ext_vector_type(8)));
typedef float f32x4 __attribute__((ext_vector_type(4)));

// ---------------- gating: logits = x @ wg (fp64 accum), top-2, renorm weights ----------------
__global__ __launch_bounds__(256) void gating_kernel(const float* __restrict__ x,
                                                     const float* __restrict__ wg,
                                                     int* __restrict__ eid,
                                                     float* __restrict__ wts) {
  int wid = threadIdx.x >> 6;
  int lane = threadIdx.x & 63;
  int s = blockIdx.x * 4 + wid;
  const float4* x4 = (const float4*)x;
  const float4* wg4 = (const float4*)wg;
  double acc[8];
#pragma unroll
  for (int e = 0; e < 8; ++e) acc[e] = 0.0;
  for (int j = 0; j < 8; ++j) {
    int v = j * 64 + lane;  // float4 index within row, 0..511
    float4 xv = x4[(size_t)s * 512 + v];
    const float4* wp = wg4 + (size_t)(v * 4) * 2;
#pragma unroll
    for (int ii = 0; ii < 4; ++ii) {
      float xs = (ii == 0) ? xv.x : (ii == 1) ? xv.y : (ii == 2) ? xv.z : xv.w;
      float4 g0 = wp[ii * 2];
      float4 g1 = wp[ii * 2 + 1];
      double xd = (double)xs;
      acc[0] += xd * (double)g0.x; acc[1] += xd * (double)g0.y;
      acc[2] += xd * (double)g0.z; acc[3] += xd * (double)g0.w;
      acc[4] += xd * (double)g1.x; acc[5] += xd * (double)g1.y;
      acc[6] += xd * (double)g1.z; acc[7] += xd * (double)g1.w;
    }
  }
#pragma unroll
  for (int e = 0; e < 8; ++e) {
    double v = acc[e];
    for (int off = 32; off > 0; off >>= 1) v += __shfl_down(v, off, 64);
    acc[e] = v;
  }
  if (lane == 0) {
    int e0 = 0; double l0 = acc[0];
    for (int e = 1; e < 8; ++e) if (acc[e] > l0) { l0 = acc[e]; e0 = e; }
    int e1 = -1; double l1 = -1e300;
    for (int e = 0; e < 8; ++e) if (e != e0 && acc[e] > l1) { l1 = acc[e]; e1 = e; }
    double pe = exp(l1 - l0);
    double inv = 1.0 / (1.0 + pe);
    eid[2 * s] = e0; eid[2 * s + 1] = e1;
    wts[2 * s] = (float)inv; wts[2 * s + 1] = (float)(pe * inv);
  }
}

// ---------------- w2s[e,h] = sum_d w2[e,h,d] ----------------
__global__ __launch_bounds__(256) void w2s_kernel(const float* __restrict__ w2,
                                                  float* __restrict__ w2s) {
  int wid = threadIdx.x >> 6, lane = threadIdx.x & 63;
  int row = blockIdx.x * 4 + wid;  // 0 .. E*H-1
  const float4* w24 = (const float4*)w2;
  float acc = 0.f;
  for (int j = 0; j < 8; ++j) {
    float4 v = w24[(size_t)row * 512 + j * 64 + lane];
    acc += v.x + v.y + v.z + v.w;
  }
  for (int off = 32; off > 0; off >>= 1) acc += __shfl_down(acc, off, 64);
  if (lane == 0) w2s[row] = acc;
}

__global__ __launch_bounds__(64) void b2s_kernel(const float* __restrict__ b2,
                                                 float* __restrict__ b2s) {
  int e = blockIdx.x; int lane = threadIdx.x;
  float acc = 0.f;
  for (int j = 0; j < 32; ++j) acc += b2[e * 2048 + j * 64 + lane];
  for (int off = 32; off > 0; off >>= 1) acc += __shfl_down(acc, off, 64);
  if (lane == 0) b2s[e] = acc;
}

// ---------------- capacity scan (deepspeed semantics), single block ----------------
__global__ __launch_bounds__(256) void scan_kernel(const int* __restrict__ eid,
                                                   int* __restrict__ locb,
                                                   int* __restrict__ slot_token) {
  __shared__ int baseLds[2][8];
  __shared__ int wcnt[2][4][8];
  __shared__ int c0tmp[8];
  int tid = threadIdx.x, wid = tid >> 6, lane = tid & 63;
  if (tid < 8) c0tmp[tid] = 0;
  __syncthreads();
  // phase A: total slot-0 counts per expert (ballot-based)
  {
    int cnt = 0;
    for (int r = 0; r < 32; ++r) {
      int s = r * 256 + tid;
      int e0 = eid[2 * s];
#pragma unroll
      for (int e = 0; e < 8; ++e) {
        unsigned long long bal = __ballot(e0 == e);
        if (lane == e) cnt += __popcll(bal);
      }
    }
    if (lane < 8) atomicAdd(&c0tmp[lane], cnt);
  }
  __syncthreads();
  if (tid < 8) { baseLds[0][tid] = 0; baseLds[1][tid] = c0tmp[tid]; }
  __syncthreads();
  unsigned long long lower = (lane == 0) ? 0ull : ((~0ull) >> (64 - lane));
  for (int r = 0; r < 32; ++r) {
    int s = r * 256 + tid;
    int e0 = eid[2 * s], e1 = eid[2 * s + 1];
    int rank0 = 0, rank1 = 0;
#pragma unroll
    for (int e = 0; e < 8; ++e) {
      unsigned long long bal0 = __ballot(e0 == e);
      unsigned long long bal1 = __ballot(e1 == e);
      if (e0 == e) rank0 = __popcll(bal0 & lower);
      if (e1 == e) rank1 = __popcll(bal1 & lower);
      if (lane == e) { wcnt[0][wid][e] = __popcll(bal0); wcnt[1][wid][e] = __popcll(bal1); }
    }
    __syncthreads();
    int loc0 = baseLds[0][e0] + rank0;
    int loc1 = baseLds[1][e1] + rank1;
    for (int w = 0; w < wid; ++w) { loc0 += wcnt[0][w][e0]; loc1 += wcnt[1][w][e1]; }
    locb[2 * s] = loc0; locb[2 * s + 1] = loc1;
    if (loc0 < CAP) slot_token[e0 * CAP + loc0] = s;
    if (loc1 < CAP) slot_token[e1 * CAP + loc1] = s;
    __syncthreads();
    if (tid < 16) {
      int k = tid >> 3, e = tid & 7;
      baseLds[k][e] += wcnt[k][0][e] + wcnt[k][1][e] + wcnt[k][2][e] + wcnt[k][3][e];
    }
    __syncthreads();
  }
}

// ---------------- gather tokens into f16 [E,C,D] ----------------
__global__ __launch_bounds__(256) void abuild_kernel(const float* __restrict__ x,
                                                     const int* __restrict__ slot_token,
                                                     f16* __restrict__ A16) {
  int slot = blockIdx.x;
  int s = slot_token[slot];
  const float4* x4 = (const float4*)x + (size_t)s * 512;
  f16x4* out = (f16x4*)(A16 + (size_t)slot * DDIM);
#pragma unroll
  for (int i = 0; i < 2; ++i) {
    int v = i * 256 + threadIdx.x;
    float4 xv = x4[v];
    f16x4 h;
    h[0] = (f16)xv.x; h[1] = (f16)xv.y; h[2] = (f16)xv.z; h[3] = (f16)xv.w;
    out[v] = h;
  }
}

// ---------------- transpose+convert w1 [E,D,H] fp32 -> [E,H,D] f16 ----------------
__global__ __launch_bounds__(256) void w1t_kernel(const float* __restrict__ w1,
                                                  f16* __restrict__ W1T) {
  __shared__ f16 tile[64 * 68];
  int b = blockIdx.x;
  int e = b >> 10; int rem = b & 1023;
  int d0 = (rem >> 5) << 6;
  int h0 = (rem & 31) << 6;
  const float4* src = (const float4*)w1;
#pragma unroll
  for (int i = 0; i < 4; ++i) {
    int linear = i * 256 + threadIdx.x;
    int r = linear >> 4, c4 = linear & 15;
    float4 v = src[((size_t)e * DDIM * HDIM + (size_t)(d0 + r) * HDIM + h0) / 4 + c4];
    int tb = r * 68 + c4 * 4;
    tile[tb + 0] = (f16)v.x; tile[tb + 1] = (f16)v.y;
    tile[tb + 2] = (f16)v.z; tile[tb + 3] = (f16)v.w;
  }
  __syncthreads();
#pragma unroll
  for (int i = 0; i < 4; ++i) {
    int linear = i * 256 + threadIdx.x;
    int hr = linear >> 4, dc4 = linear & 15;
    f16x4 o;
    o[0] = tile[(dc4 * 4 + 0) * 68 + hr];
    o[1] = tile[(dc4 * 4 + 1) * 68 + hr];
    o[2] = tile[(dc4 * 4 + 2) * 68 + hr];
    o[3] = tile[(dc4 * 4 + 3) * 68 + hr];
    *(f16x4*)(W1T + (size_t)e * HDIM * DDIM + (size_t)(h0 + hr) * DDIM + d0 + dc4 * 4) = o;
  }
}

// ---------------- GEMM1 + bias + relu + w2s-dot epilogue ----------------
__global__ __launch_bounds__(256) void gemm_kernel(const f16* __restrict__ A16,
                                                   const f16* __restrict__ W1T,
                                                   const float* __restrict__ b1,
                                                   const float* __restrict__ w2s,
                                                   float* __restrict__ zacc) {
  __shared__ __align__(16) f16 As[128 * 32];
  __shared__ __align__(16) f16 Bs[128 * 32];
  int tid = threadIdx.x;
  int wid = tid >> 6, lane = tid & 63;
  int cT = blockIdx.x, hT = blockIdx.y, e = blockIdx.z;
  int c0 = cT * 128, h0 = hT * 128;
  const f16* Abase = A16 + ((size_t)e * CAP + c0) * DDIM;
  const f16* Bbase = W1T + ((size_t)e * HDIM + h0) * DDIM;
  f32x4 acc[4][4];
#pragma unroll
  for (int i = 0; i < 4; ++i)
#pragma unroll
    for (int j = 0; j < 4; ++j) acc[i][j] = (f32x4){0.f, 0.f, 0.f, 0.f};
  int wm = (wid >> 1) * 64, wn = (wid & 1) * 64;
  int quad = lane >> 4, l15 = lane & 15;

  for (int k0 = 0; k0 < DDIM; k0 += 32) {
    __syncthreads();
#pragma unroll
    for (int i = 0; i < 2; ++i) {
      int off = (i * 256 + tid) * 8;  // f16 offset in 128x32 tile
      int row = off >> 5, col = off & 31;
      *(uint4*)&As[off] = *(const uint4*)&Abase[(size_t)row * DDIM + k0 + col];
      *(uint4*)&Bs[off] = *(const uint4*)&Bbase[(size_t)row * DDIM + k0 + col];
    }
    __syncthreads();
    f16x8 af[4], bfr[4];
#pragma unroll
    for (int mt = 0; mt < 4; ++mt)
      af[mt] = *(const f16x8*)&As[(wm + mt * 16 + l15) * 32 + quad * 8];
#pragma unroll
    for (int nt = 0; nt < 4; ++nt)
      bfr[nt] = *(const f16x8*)&Bs[(wn + nt * 16 + l15) * 32 + quad * 8];
#pragma unroll
    for (int mt = 0; mt < 4; ++mt)
#pragma unroll
      for (int nt = 0; nt < 4; ++nt)
        acc[mt][nt] = __builtin_amdgcn_mfma_f32_16x16x32_f16(af[mt], bfr[nt], acc[mt][nt], 0, 0, 0);
  }
  // epilogue: rowsum over h of relu(acc + b1) * w2s
  float b1v[4], wsv[4];
#pragma unroll
  for (int nt = 0; nt < 4; ++nt) {
    int h = h0 + wn + nt * 16 + l15;
    b1v[nt] = b1[e * HDIM + h];
    wsv[nt] = w2s[e * HDIM + h];
  }
#pragma unroll
  for (int mt = 0; mt < 4; ++mt) {
    float pr[4];
#pragma unroll
    for (int r = 0; r < 4; ++r) {
      float t = 0.f;
#pragma unroll
      for (int nt = 0; nt < 4; ++nt) {
        float v = acc[mt][nt][r] + b1v[nt];
        t += (v > 0.f ? v : 0.f) * wsv[nt];
      }
      pr[r] = t;
    }
#pragma unroll
    for (int r = 0; r < 4; ++r)
#pragma unroll
      for (int off = 1; off < 16; off <<= 1) pr[r] += __shfl_xor(pr[r], off, 64);
    if (l15 == 0) {
      int m = c0 + wm + mt * 16 + quad * 4;
#pragma unroll
      for (int r = 0; r < 4; ++r) atomicAdd(&zacc[e * CAP + m + r], pr[r]);
    }
  }
}

// ---------------- combine: z[s] = sum_k valid * w * (zacc + b2s) ----------------
__global__ __launch_bounds__(256) void combine_kernel(const int* __restrict__ eid,
                                                      const int* __restrict__ locb,
                                                      const float* __restrict__ wts,
                                                      const float* __restrict__ zacc,
                                                      const float* __restrict__ b2s,
                                                      float* __restrict__ z) {
  int s = blockIdx.x * 256 + threadIdx.x;
  float zz = 0.f;
#pragma unroll
  for (int k = 0; k < 2; ++k) {
    int e = eid[2 * s + k], loc = locb[2 * s + k];
    if (loc < CAP) zz += wts[2 * s + k] * (zacc[e * CAP + loc] + b2s[e]);
  }
  z[s] = zz;
}

// ---------------- per-batch-row log_softmax over T ----------------
__global__ __launch_bounds__(256) void lsm_kernel(const float* __restrict__ z,
                                                  float* __restrict__ out) {
  __shared__ float red[4];
  int b = blockIdx.x, tid = threadIdx.x;
  int wid = tid >> 6, lane = tid & 63;
  const float* zr = z + b * TT;
  float v[8];
  float mx = -1e30f;
#pragma unroll
  for (int i = 0; i < 8; ++i) { v[i] = zr[i * 256 + tid]; mx = fmaxf(mx, v[i]); }
  for (int off = 32; off > 0; off >>= 1) mx = fmaxf(mx, __shfl_xor(mx, off, 64));
  if (lane == 0) red[wid] = mx;
  __syncthreads();
  mx = fmaxf(fmaxf(red[0], red[1]), fmaxf(red[2], red[3]));
  float sum = 0.f;
#pragma unroll
  for (int i = 0; i < 8; ++i) sum += expf(v[i] - mx);
  for (int off = 32; off > 0; off >>= 1) sum += __shfl_xor(sum, off, 64);
  __syncthreads();
  if (lane == 0) red[wid] = sum;
  __syncthreads();
  sum = red[0] + red[1] + red[2] + red[3];
  float lse = mx + logf(sum);
#pragma unroll
  for (int i = 0; i < 8; ++i) out[b * TT + i * 256 + tid] = v[i] - lse;
}

extern "C" void kernel_launch(void* const* d_in, const int* in_sizes, int n_in,
                              void* d_out, int out_size, void* d_ws, size_t ws_size,
                              hipStream_t stream) {
  const float* x  = (const float*)d_in[0];
  const float* wg = (const float*)d_in[1];
  const float* w1 = (const float*)d_in[2];
  const float* b1 = (const float*)d_in[3];
  const float* w2 = (const float*)d_in[4];
  const float* b2 = (const float*)d_in[5];
  float* out = (float*)d_out;

  char* ws = (char*)d_ws;
  size_t off = 0;
  auto alloc = [&](size_t bytes) -> char* {
    char* p = ws + off;
    off += (bytes + 255) & ~(size_t)255;
    return p;
  };
  f16* A16 = (f16*)alloc((size_t)NE * CAP * DDIM * 2);
  f16* W1T = (f16*)alloc((size_t)NE * HDIM * DDIM * 2);
  float* w2s = (float*)alloc((size_t)NE * HDIM * 4);
  float* b2s = (float*)alloc(NE * 4);
  int* eid = (int*)alloc((size_t)S_TOK * 2 * 4);
  float* wts = (float*)alloc((size_t)S_TOK * 2 * 4);
  int* locb = (int*)alloc((size_t)S_TOK * 2 * 4);
  int* slot_token = (int*)alloc((size_t)NE * CAP * 4);
  float* zacc = (float*)alloc((size_t)NE * CAP * 4);
  float* z = (float*)alloc((size_t)S_TOK * 4);
  if (off > ws_size) return;  // workspace too small: fail loudly via wrong output

  hipMemsetAsync(slot_token, 0, NE * CAP * 4, stream);
  hipMemsetAsync(zacc, 0, NE * CAP * 4, stream);

  gating_kernel<<<S_TOK / 4, 256, 0, stream>>>(x, wg, eid, wts);
  w2s_kernel<<<NE * HDIM / 4, 256, 0, stream>>>(w2, w2s);
  b2s_kernel<<<NE, 64, 0, stream>>>(b2, b2s);
  scan_kernel<<<1, 256, 0, stream>>>(eid, locb, slot_token);
  abuild_kernel<<<NE * CAP, 256, 0, stream>>>(x, slot_token, A16);
  w1t_kernel<<<NE * 32 * 32, 256, 0, stream>>>(w1, W1T);
  gemm_kernel<<<dim3(CAP / 128, HDIM / 128, NE), 256, 0, stream>>>(A16, W1T, b1, w2s, zacc);
  combine_kernel<<<S_TOK / 256, 256, 0, stream>>>(eid, locb, wts, zacc, b2s, z);
  lsm_kernel<<<NBATCH, 256, 0, stream>>>(z, out);
}

// Round 3
// 618.689 us; speedup vs baseline: 1.0517x; 1.0517x over previous
//
#include <hip/hip_runtime.h>
#include <math.h>

#define S_TOK 8192
#define DDIM 2048
#define HDIM 2048
#define NE 8
#define CAP 2048
#define NBATCH 4
#define TT 2048

typedef _Float16 f16;
typedef _Float16 f16x4 __attribute__((ext_vector_type(4)));
typedef _Float16 f16x8 __attribute__((ext_vector_type(8)));
typedef float f32x4 __attribute__((ext_vector_type(4)));

typedef __attribute__((address_space(1))) const void* gas_ptr;
typedef __attribute__((address_space(3))) void* las_ptr;

// ---------------- gating: logits = x @ wg (fp64 accum), top-2, renorm weights ----------------
// also zero-inits slot_token and zacc (blocks 0..63) so no separate memsets are needed
__global__ __launch_bounds__(256) void gating_kernel(const float* __restrict__ x,
                                                     const float* __restrict__ wg,
                                                     int* __restrict__ eid,
                                                     float* __restrict__ wts,
                                                     int* __restrict__ slot_token,
                                                     float* __restrict__ zacc) {
  if (blockIdx.x < 64) {
    int i = blockIdx.x * 256 + threadIdx.x;
    slot_token[i] = 0;
    zacc[i] = 0.f;
  }
  int wid = threadIdx.x >> 6;
  int lane = threadIdx.x & 63;
  int s = blockIdx.x * 4 + wid;
  const float4* x4 = (const float4*)x;
  const float4* wg4 = (const float4*)wg;
  double acc[8];
#pragma unroll
  for (int e = 0; e < 8; ++e) acc[e] = 0.0;
  for (int j = 0; j < 8; ++j) {
    int v = j * 64 + lane;  // float4 index within row, 0..511
    float4 xv = x4[(size_t)s * 512 + v];
    const float4* wp = wg4 + (size_t)(v * 4) * 2;
#pragma unroll
    for (int ii = 0; ii < 4; ++ii) {
      float xs = (ii == 0) ? xv.x : (ii == 1) ? xv.y : (ii == 2) ? xv.z : xv.w;
      float4 g0 = wp[ii * 2];
      float4 g1 = wp[ii * 2 + 1];
      double xd = (double)xs;
      acc[0] += xd * (double)g0.x; acc[1] += xd * (double)g0.y;
      acc[2] += xd * (double)g0.z; acc[3] += xd * (double)g0.w;
      acc[4] += xd * (double)g1.x; acc[5] += xd * (double)g1.y;
      acc[6] += xd * (double)g1.z; acc[7] += xd * (double)g1.w;
    }
  }
#pragma unroll
  for (int e = 0; e < 8; ++e) {
    double v = acc[e];
    for (int off = 32; off > 0; off >>= 1) v += __shfl_down(v, off, 64);
    acc[e] = v;
  }
  if (lane == 0) {
    int e0 = 0; double l0 = acc[0];
    for (int e = 1; e < 8; ++e) if (acc[e] > l0) { l0 = acc[e]; e0 = e; }
    int e1 = -1; double l1 = -1e300;
    for (int e = 0; e < 8; ++e) if (e != e0 && acc[e] > l1) { l1 = acc[e]; e1 = e; }
    double pe = exp(l1 - l0);
    double inv = 1.0 / (1.0 + pe);
    eid[2 * s] = e0; eid[2 * s + 1] = e1;
    wts[2 * s] = (float)inv; wts[2 * s + 1] = (float)(pe * inv);
  }
}

// ---------------- capacity scan (deepspeed semantics), single block ----------------
__global__ __launch_bounds__(256) void scan_kernel(const int* __restrict__ eid,
                                                   int* __restrict__ locb,
                                                   int* __restrict__ slot_token) {
  __shared__ int baseLds[2][8];
  __shared__ int wcnt[2][4][8];
  __shared__ int c0tmp[8];
  int tid = threadIdx.x, wid = tid >> 6, lane = tid & 63;
  if (tid < 8) c0tmp[tid] = 0;
  __syncthreads();
  {
    int cnt = 0;
    for (int r = 0; r < 32; ++r) {
      int s = r * 256 + tid;
      int e0 = eid[2 * s];
#pragma unroll
      for (int e = 0; e < 8; ++e) {
        unsigned long long bal = __ballot(e0 == e);
        if (lane == e) cnt += __popcll(bal);
      }
    }
    if (lane < 8) atomicAdd(&c0tmp[lane], cnt);
  }
  __syncthreads();
  if (tid < 8) { baseLds[0][tid] = 0; baseLds[1][tid] = c0tmp[tid]; }
  __syncthreads();
  unsigned long long lower = (lane == 0) ? 0ull : ((~0ull) >> (64 - lane));
  for (int r = 0; r < 32; ++r) {
    int s = r * 256 + tid;
    int e0 = eid[2 * s], e1 = eid[2 * s + 1];
    int rank0 = 0, rank1 = 0;
#pragma unroll
    for (int e = 0; e < 8; ++e) {
      unsigned long long bal0 = __ballot(e0 == e);
      unsigned long long bal1 = __ballot(e1 == e);
      if (e0 == e) rank0 = __popcll(bal0 & lower);
      if (e1 == e) rank1 = __popcll(bal1 & lower);
      if (lane == e) { wcnt[0][wid][e] = __popcll(bal0); wcnt[1][wid][e] = __popcll(bal1); }
    }
    __syncthreads();
    int loc0 = baseLds[0][e0] + rank0;
    int loc1 = baseLds[1][e1] + rank1;
    for (int w = 0; w < wid; ++w) { loc0 += wcnt[0][w][e0]; loc1 += wcnt[1][w][e1]; }
    locb[2 * s] = loc0; locb[2 * s + 1] = loc1;
    if (loc0 < CAP) slot_token[e0 * CAP + loc0] = s;
    if (loc1 < CAP) slot_token[e1 * CAP + loc1] = s;
    __syncthreads();
    if (tid < 16) {
      int k = tid >> 3, e = tid & 7;
      baseLds[k][e] += wcnt[k][0][e] + wcnt[k][1][e] + wcnt[k][2][e] + wcnt[k][3][e];
    }
    __syncthreads();
  }
}

// ---------------- fused prep: w1 transpose->f16, w2 rowsum, b2 sum, A16 gather ----------------
// blocks [0,8192): w1t ; [8192,12288): w2s ; 12288: b2s ; [12289, 12289+16384): abuild
#define W1T_BLOCKS 8192
#define W2S_BLOCKS 4096
#define ABUILD_BASE (W1T_BLOCKS + W2S_BLOCKS + 1)
__global__ __launch_bounds__(256) void prep_kernel(const float* __restrict__ w1,
                                                   const float* __restrict__ w2,
                                                   const float* __restrict__ b2,
                                                   const float* __restrict__ x,
                                                   const int* __restrict__ slot_token,
                                                   f16* __restrict__ W1T,
                                                   float* __restrict__ w2s,
                                                   float* __restrict__ b2s,
                                                   f16* __restrict__ A16) {
  __shared__ float tile[64 * 65];  // 16.6 KB, +1 padding -> conflict-free transpose
  int bid = blockIdx.x, tid = threadIdx.x;
  if (bid >= ABUILD_BASE) {
    // ---- abuild: gather token rows into f16 [E,C,D] ----
    int slot = bid - ABUILD_BASE;
    int s = slot_token[slot];
    const float4* x4 = (const float4*)x + (size_t)s * 512;
    f16x4* outp = (f16x4*)(A16 + (size_t)slot * DDIM);
#pragma unroll
    for (int i = 0; i < 2; ++i) {
      int v = i * 256 + tid;
      float4 xv = x4[v];
      f16x4 h;
      h[0] = (f16)xv.x; h[1] = (f16)xv.y; h[2] = (f16)xv.z; h[3] = (f16)xv.w;
      outp[v] = h;
    }
    return;
  }
  if (bid < W1T_BLOCKS) {
    // ---- w1t: [E,D,H] fp32 -> [E,H,D] f16 via padded fp32 LDS tile ----
    int e = bid >> 10, rem = bid & 1023;
    int d0 = (rem >> 5) << 6;
    int h0 = (rem & 31) << 6;
    const float* w1e = w1 + (size_t)e * DDIM * HDIM;
#pragma unroll
    for (int i = 0; i < 4; ++i) {
      int linear = i * 256 + tid;       // 1024 float4 slots = 64 rows x 16
      int r = linear >> 4, c4 = linear & 15;
      float4 v = *(const float4*)(w1e + (size_t)(d0 + r) * HDIM + h0 + c4 * 4);
      float* t = &tile[r * 65 + c4 * 4];
      t[0] = v.x; t[1] = v.y; t[2] = v.z; t[3] = v.w;
    }
    __syncthreads();
    f16* W1Te = W1T + (size_t)e * HDIM * DDIM;
#pragma unroll
    for (int i = 0; i < 2; ++i) {
      int linear = i * 256 + tid;       // 512 slots = 64 h-rows x 8 lanes
      int hr = linear >> 3, l8 = linear & 7;
      f16x8 o;
#pragma unroll
      for (int j = 0; j < 8; ++j) o[j] = (f16)tile[(l8 * 8 + j) * 65 + hr];
      *(f16x8*)(W1Te + (size_t)(h0 + hr) * DDIM + d0 + l8 * 8) = o;
    }
    return;
  }
  if (bid < W1T_BLOCKS + W2S_BLOCKS) {
    // ---- w2s[e,h] = sum_d w2[e,h,d], one row per wave ----
    int wid = tid >> 6, lane = tid & 63;
    int row = (bid - W1T_BLOCKS) * 4 + wid;
    const float4* w24 = (const float4*)w2;
    float acc = 0.f;
    for (int j = 0; j < 8; ++j) {
      float4 v = w24[(size_t)row * 512 + j * 64 + lane];
      acc += v.x + v.y + v.z + v.w;
    }
    for (int off = 32; off > 0; off >>= 1) acc += __shfl_down(acc, off, 64);
    if (lane == 0) w2s[row] = acc;
    return;
  }
  // ---- b2s: 8 experts, 32 lanes each ----
  {
    int e = tid >> 5, l32 = tid & 31;
    float acc = 0.f;
    for (int j = 0; j < 64; ++j) acc += b2[e * 2048 + j * 32 + l32];
    for (int off = 16; off > 0; off >>= 1) acc += __shfl_down(acc, off, 32);
    if (l32 == 0) b2s[e] = acc;
  }
}

// ---------------- GEMM1 (global_load_lds builtin staging) + bias + relu + w2s-dot epilogue ----------------
__global__ __launch_bounds__(256) void gemm_kernel(const f16* __restrict__ A16,
                                                   const f16* __restrict__ W1T,
                                                   const float* __restrict__ b1,
                                                   const float* __restrict__ w2s,
                                                   float* __restrict__ zacc) {
  __shared__ __align__(16) f16 As[128 * 32];
  __shared__ __align__(16) f16 Bs[128 * 32];
  int tid = threadIdx.x;
  int wid = tid >> 6, lane = tid & 63;
  // 4x4 supertile swizzle over 1-D grid for L2 locality
  int bid = blockIdx.x;
  int e = bid >> 8;
  int r = bid & 255;
  int st = r >> 4, wi = r & 15;
  int cT = (st >> 2) * 4 + (wi >> 2);
  int hT = (st & 3) * 4 + (wi & 3);
  int c0 = cT * 128, h0 = hT * 128;
  const f16* Abase = A16 + ((size_t)e * CAP + c0) * DDIM;
  const f16* Bbase = W1T + ((size_t)e * HDIM + h0) * DDIM;
  f32x4 acc[4][4];
#pragma unroll
  for (int i = 0; i < 4; ++i)
#pragma unroll
    for (int j = 0; j < 4; ++j) acc[i][j] = (f32x4){0.f, 0.f, 0.f, 0.f};
  int wm = (wid >> 1) * 64, wn = (wid & 1) * 64;
  int quad = lane >> 4, l15 = lane & 15;

  // DMA staging: wave wid owns rows [wid*32, wid*32+32) of both 128x32 tiles.
  // One global_load_lds_dwordx4 covers 16 rows: lane i loads row i/4, col (i%4)*8 f16,
  // and HW deposits at lds_base + i*16 -> row-major contiguous. 2 instrs per tile per wave.
  const f16* Aln = Abase + (size_t)(wid * 32 + (lane >> 2)) * DDIM + (lane & 3) * 8;
  const f16* Bln = Bbase + (size_t)(wid * 32 + (lane >> 2)) * DDIM + (lane & 3) * 8;
  f16* ldsA0 = &As[wid * 1024];        // wid*32 rows * 32 f16
  f16* ldsA1 = &As[wid * 1024 + 512];  // +16 rows
  f16* ldsB0 = &Bs[wid * 1024];
  f16* ldsB1 = &Bs[wid * 1024 + 512];

  for (int k0 = 0; k0 < DDIM; k0 += 32) {
    __syncthreads();  // previous tile fully consumed
    __builtin_amdgcn_global_load_lds((gas_ptr)(Aln + k0), (las_ptr)ldsA0, 16, 0, 0);
    __builtin_amdgcn_global_load_lds((gas_ptr)(Aln + k0 + 16 * DDIM), (las_ptr)ldsA1, 16, 0, 0);
    __builtin_amdgcn_global_load_lds((gas_ptr)(Bln + k0), (las_ptr)ldsB0, 16, 0, 0);
    __builtin_amdgcn_global_load_lds((gas_ptr)(Bln + k0 + 16 * DDIM), (las_ptr)ldsB1, 16, 0, 0);
    __syncthreads();  // compiler drains vmcnt(0) before barrier: DMA data visible
    f16x8 af[4], bfr[4];
#pragma unroll
    for (int mt = 0; mt < 4; ++mt)
      af[mt] = *(const f16x8*)&As[(wm + mt * 16 + l15) * 32 + quad * 8];
#pragma unroll
    for (int nt = 0; nt < 4; ++nt)
      bfr[nt] = *(const f16x8*)&Bs[(wn + nt * 16 + l15) * 32 + quad * 8];
#pragma unroll
    for (int mt = 0; mt < 4; ++mt)
#pragma unroll
      for (int nt = 0; nt < 4; ++nt)
        acc[mt][nt] = __builtin_amdgcn_mfma_f32_16x16x32_f16(af[mt], bfr[nt], acc[mt][nt], 0, 0, 0);
  }
  // epilogue: rowsum over h of relu(acc + b1) * w2s
  float b1v[4], wsv[4];
#pragma unroll
  for (int nt = 0; nt < 4; ++nt) {
    int h = h0 + wn + nt * 16 + l15;
    b1v[nt] = b1[e * HDIM + h];
    wsv[nt] = w2s[e * HDIM + h];
  }
#pragma unroll
  for (int mt = 0; mt < 4; ++mt) {
    float pr[4];
#pragma unroll
    for (int rr = 0; rr < 4; ++rr) {
      float t = 0.f;
#pragma unroll
      for (int nt = 0; nt < 4; ++nt) {
        float v = acc[mt][nt][rr] + b1v[nt];
        t += (v > 0.f ? v : 0.f) * wsv[nt];
      }
      pr[rr] = t;
    }
#pragma unroll
    for (int rr = 0; rr < 4; ++rr)
#pragma unroll
      for (int off = 1; off < 16; off <<= 1) pr[rr] += __shfl_xor(pr[rr], off, 64);
    if (l15 == 0) {
      int m = c0 + wm + mt * 16 + quad * 4;
#pragma unroll
      for (int rr = 0; rr < 4; ++rr) atomicAdd(&zacc[e * CAP + m + rr], pr[rr]);
    }
  }
}

// ---------------- fused combine + per-batch-row log_softmax ----------------
__global__ __launch_bounds__(256) void tail_kernel(const int* __restrict__ eid,
                                                   const int* __restrict__ locb,
                                                   const float* __restrict__ wts,
                                                   const float* __restrict__ zacc,
                                                   const float* __restrict__ b2s,
                                                   float* __restrict__ out) {
  __shared__ float red[4];
  int b = blockIdx.x, tid = threadIdx.x;
  int wid = tid >> 6, lane = tid & 63;
  float v[8];
  float mx = -1e30f;
#pragma unroll
  for (int i = 0; i < 8; ++i) {
    int s = b * TT + i * 256 + tid;
    float zz = 0.f;
#pragma unroll
    for (int k = 0; k < 2; ++k) {
      int e = eid[2 * s + k], loc = locb[2 * s + k];
      if (loc < CAP) zz += wts[2 * s + k] * (zacc[e * CAP + loc] + b2s[e]);
    }
    v[i] = zz;
    mx = fmaxf(mx, zz);
  }
  for (int off = 32; off > 0; off >>= 1) mx = fmaxf(mx, __shfl_xor(mx, off, 64));
  if (lane == 0) red[wid] = mx;
  __syncthreads();
  mx = fmaxf(fmaxf(red[0], red[1]), fmaxf(red[2], red[3]));
  float sum = 0.f;
#pragma unroll
  for (int i = 0; i < 8; ++i) sum += expf(v[i] - mx);
  for (int off = 32; off > 0; off >>= 1) sum += __shfl_xor(sum, off, 64);
  __syncthreads();
  if (lane == 0) red[wid] = sum;
  __syncthreads();
  sum = red[0] + red[1] + red[2] + red[3];
  float lse = mx + logf(sum);
#pragma unroll
  for (int i = 0; i < 8; ++i) out[b * TT + i * 256 + tid] = v[i] - lse;
}

extern "C" void kernel_launch(void* const* d_in, const int* in_sizes, int n_in,
                              void* d_out, int out_size, void* d_ws, size_t ws_size,
                              hipStream_t stream) {
  const float* x  = (const float*)d_in[0];
  const float* wg = (const float*)d_in[1];
  const float* w1 = (const float*)d_in[2];
  const float* b1 = (const float*)d_in[3];
  const float* w2 = (const float*)d_in[4];
  const float* b2 = (const float*)d_in[5];
  float* out = (float*)d_out;

  char* ws = (char*)d_ws;
  size_t off = 0;
  auto alloc = [&](size_t bytes) -> char* {
    char* p = ws + off;
    off += (bytes + 255) & ~(size_t)255;
    return p;
  };
  f16* A16 = (f16*)alloc((size_t)NE * CAP * DDIM * 2);
  f16* W1T = (f16*)alloc((size_t)NE * HDIM * DDIM * 2);
  float* w2s = (float*)alloc((size_t)NE * HDIM * 4);
  float* b2s = (float*)alloc(NE * 4);
  int* eid = (int*)alloc((size_t)S_TOK * 2 * 4);
  float* wts = (float*)alloc((size_t)S_TOK * 2 * 4);
  int* locb = (int*)alloc((size_t)S_TOK * 2 * 4);
  int* slot_token = (int*)alloc((size_t)NE * CAP * 4);
  float* zacc = (float*)alloc((size_t)NE * CAP * 4);
  if (off > ws_size) return;  // workspace too small: fail loudly via wrong output

  gating_kernel<<<S_TOK / 4, 256, 0, stream>>>(x, wg, eid, wts, slot_token, zacc);
  scan_kernel<<<1, 256, 0, stream>>>(eid, locb, slot_token);
  prep_kernel<<<ABUILD_BASE + NE * CAP, 256, 0, stream>>>(w1, w2, b2, x, slot_token,
                                                          W1T, w2s, b2s, A16);
  gemm_kernel<<<NE * 256, 256, 0, stream>>>(A16, W1T, b1, w2s, zacc);
  tail_kernel<<<NBATCH, 256, 0, stream>>>(eid, locb, wts, zacc, b2s, out);
}

// Round 4
// 592.886 us; speedup vs baseline: 1.0975x; 1.0435x over previous
//
#include <hip/hip_runtime.h>
#include <math.h>

#define S_TOK 8192
#define DDIM 2048
#define HDIM 2048
#define NE 8
#define CAP 2048
#define NBATCH 4
#define TT 2048

typedef _Float16 f16;
typedef _Float16 f16x4 __attribute__((ext_vector_type(4)));
typedef _Float16 f16x8 __attribute__((ext_vector_type(8)));
typedef float f32x4 __attribute__((ext_vector_type(4)));

typedef __attribute__((address_space(1))) const void* gas_ptr;
typedef __attribute__((address_space(3))) void* las_ptr;

// ---------------- gating: logits = x @ wg (fp64 accum), top-2, renorm weights ----------------
// lane <-> d mapping: x reads 256B coalesced, wg reads 32B/lane contiguous (2KB/instr).
// also zero-inits slot_token and zacc (blocks 0..63) so no separate memsets are needed
__global__ __launch_bounds__(256) void gating_kernel(const float* __restrict__ x,
                                                     const float* __restrict__ wg,
                                                     int* __restrict__ eid,
                                                     float* __restrict__ wts,
                                                     int* __restrict__ slot_token,
                                                     float* __restrict__ zacc) {
  if (blockIdx.x < 64) {
    int i = blockIdx.x * 256 + threadIdx.x;
    slot_token[i] = 0;
    zacc[i] = 0.f;
  }
  int wid = threadIdx.x >> 6;
  int lane = threadIdx.x & 63;
  int s = blockIdx.x * 4 + wid;
  const float* xr = x + (size_t)s * DDIM;
  double acc[8];
#pragma unroll
  for (int e = 0; e < 8; ++e) acc[e] = 0.0;
  for (int d0 = 0; d0 < DDIM; d0 += 64) {
    float xs = xr[d0 + lane];
    const float4* wp = (const float4*)(wg + (size_t)(d0 + lane) * 8);
    float4 g0 = wp[0];
    float4 g1 = wp[1];
    double xd = (double)xs;
    acc[0] += xd * (double)g0.x; acc[1] += xd * (double)g0.y;
    acc[2] += xd * (double)g0.z; acc[3] += xd * (double)g0.w;
    acc[4] += xd * (double)g1.x; acc[5] += xd * (double)g1.y;
    acc[6] += xd * (double)g1.z; acc[7] += xd * (double)g1.w;
  }
#pragma unroll
  for (int e = 0; e < 8; ++e) {
    double v = acc[e];
    for (int off = 32; off > 0; off >>= 1) v += __shfl_down(v, off, 64);
    acc[e] = v;
  }
  if (lane == 0) {
    int e0 = 0; double l0 = acc[0];
    for (int e = 1; e < 8; ++e) if (acc[e] > l0) { l0 = acc[e]; e0 = e; }
    int e1 = -1; double l1 = -1e300;
    for (int e = 0; e < 8; ++e) if (e != e0 && acc[e] > l1) { l1 = acc[e]; e1 = e; }
    double pe = exp(l1 - l0);
    double inv = 1.0 / (1.0 + pe);
    eid[2 * s] = e0; eid[2 * s + 1] = e1;
    wts[2 * s] = (float)inv; wts[2 * s + 1] = (float)(pe * inv);
  }
}

// ---------------- capacity scan (deepspeed semantics): 4 waves, two-phase, 1 barrier ----------------
// wave w owns tokens [w*2048,(w+1)*2048). Phase 1: per-wave per-expert counts (ballot).
// Prefix: base0[w][e]=sum_{w'<w}c0 ; base1[w][e]=total0[e]+sum_{w'<w}c1 (slot-1 offset by ALL slot-0).
// Phase 2: replay with running bases in LDS (wave-internal DS ordering, no barriers).
__global__ __launch_bounds__(256) void scan_kernel(const int* __restrict__ eid,
                                                   int* __restrict__ locb,
                                                   int* __restrict__ slot_token) {
  __shared__ int seg[4][2][8];
  __shared__ int base[4][2][8];
  int tid = threadIdx.x, wid = tid >> 6, lane = tid & 63;
  unsigned long long lower = (lane == 0) ? 0ull : ((~0ull) >> (64 - lane));
  const int2* eid2 = (const int2*)eid;
  int c0 = 0, c1 = 0;  // valid in lanes 0..7 (expert == lane)
  for (int r = 0; r < 32; ++r) {
    int2 ee = eid2[wid * 2048 + r * 64 + lane];
#pragma unroll
    for (int e = 0; e < 8; ++e) {
      unsigned long long b0 = __ballot(ee.x == e);
      unsigned long long b1 = __ballot(ee.y == e);
      if (lane == e) { c0 += __popcll(b0); c1 += __popcll(b1); }
    }
  }
  if (lane < 8) { seg[wid][0][lane] = c0; seg[wid][1][lane] = c1; }
  __syncthreads();
  if (lane < 8) {
    int e = lane;
    int tot0 = seg[0][0][e] + seg[1][0][e] + seg[2][0][e] + seg[3][0][e];
    int b0 = 0, b1 = tot0;
    for (int w = 0; w < wid; ++w) { b0 += seg[w][0][e]; b1 += seg[w][1][e]; }
    base[wid][0][e] = b0; base[wid][1][e] = b1;
  }
  // base[wid] written and read only by wave wid; DS ops are in-order per wave -> no barrier.
  for (int r = 0; r < 32; ++r) {
    int2 ee = eid2[wid * 2048 + r * 64 + lane];
    int rank0 = 0, rank1 = 0, add0 = 0, add1 = 0;
#pragma unroll
    for (int e = 0; e < 8; ++e) {
      unsigned long long b0 = __ballot(ee.x == e);
      unsigned long long b1 = __ballot(ee.y == e);
      if (ee.x == e) rank0 = __popcll(b0 & lower);
      if (ee.y == e) rank1 = __popcll(b1 & lower);
      if (lane == e) { add0 = __popcll(b0); add1 = __popcll(b1); }
    }
    int loc0 = base[wid][0][ee.x] + rank0;
    int loc1 = base[wid][1][ee.y] + rank1;
    int s = wid * 2048 + r * 64 + lane;
    int2 lo; lo.x = loc0; lo.y = loc1;
    *(int2*)&locb[2 * s] = lo;
    if (loc0 < CAP) slot_token[ee.x * CAP + loc0] = s;
    if (loc1 < CAP) slot_token[ee.y * CAP + loc1] = s;
    if (lane < 8) {
      atomicAdd(&base[wid][0][lane], add0);
      atomicAdd(&base[wid][1][lane], add1);
    }
  }
}

// ---------------- fused prep: w1 transpose->f16, w2 rowsum, b2 sum, A16 gather ----------------
// blocks [0,8192): w1t ; [8192,12288): w2s ; 12288: b2s ; [12289, 12289+16384): abuild
#define W1T_BLOCKS 8192
#define W2S_BLOCKS 4096
#define ABUILD_BASE (W1T_BLOCKS + W2S_BLOCKS + 1)
__global__ __launch_bounds__(256) void prep_kernel(const float* __restrict__ w1,
                                                   const float* __restrict__ w2,
                                                   const float* __restrict__ b2,
                                                   const float* __restrict__ x,
                                                   const int* __restrict__ slot_token,
                                                   f16* __restrict__ W1T,
                                                   float* __restrict__ w2s,
                                                   float* __restrict__ b2s,
                                                   f16* __restrict__ A16) {
  __shared__ float tile[64 * 65];  // 16.6 KB, +1 padding -> conflict-free transpose
  int bid = blockIdx.x, tid = threadIdx.x;
  if (bid >= ABUILD_BASE) {
    // ---- abuild: gather token rows into f16 [E,C,D] ----
    int slot = bid - ABUILD_BASE;
    int s = slot_token[slot];
    const float4* x4 = (const float4*)x + (size_t)s * 512;
    f16x4* outp = (f16x4*)(A16 + (size_t)slot * DDIM);
#pragma unroll
    for (int i = 0; i < 2; ++i) {
      int v = i * 256 + tid;
      float4 xv = x4[v];
      f16x4 h;
      h[0] = (f16)xv.x; h[1] = (f16)xv.y; h[2] = (f16)xv.z; h[3] = (f16)xv.w;
      outp[v] = h;
    }
    return;
  }
  if (bid < W1T_BLOCKS) {
    // ---- w1t: [E,D,H] fp32 -> [E,H,D] f16 via padded fp32 LDS tile ----
    int e = bid >> 10, rem = bid & 1023;
    int d0 = (rem >> 5) << 6;
    int h0 = (rem & 31) << 6;
    const float* w1e = w1 + (size_t)e * DDIM * HDIM;
#pragma unroll
    for (int i = 0; i < 4; ++i) {
      int linear = i * 256 + tid;       // 1024 float4 slots = 64 rows x 16
      int r = linear >> 4, c4 = linear & 15;
      float4 v = *(const float4*)(w1e + (size_t)(d0 + r) * HDIM + h0 + c4 * 4);
      float* t = &tile[r * 65 + c4 * 4];
      t[0] = v.x; t[1] = v.y; t[2] = v.z; t[3] = v.w;
    }
    __syncthreads();
    f16* W1Te = W1T + (size_t)e * HDIM * DDIM;
#pragma unroll
    for (int i = 0; i < 2; ++i) {
      int linear = i * 256 + tid;       // 512 slots = 64 h-rows x 8 lanes
      int hr = linear >> 3, l8 = linear & 7;
      f16x8 o;
#pragma unroll
      for (int j = 0; j < 8; ++j) o[j] = (f16)tile[(l8 * 8 + j) * 65 + hr];
      *(f16x8*)(W1Te + (size_t)(h0 + hr) * DDIM + d0 + l8 * 8) = o;
    }
    return;
  }
  if (bid < W1T_BLOCKS + W2S_BLOCKS) {
    // ---- w2s[e,h] = sum_d w2[e,h,d], one row per wave ----
    int wid = tid >> 6, lane = tid & 63;
    int row = (bid - W1T_BLOCKS) * 4 + wid;
    const float4* w24 = (const float4*)w2;
    float acc = 0.f;
    for (int j = 0; j < 8; ++j) {
      float4 v = w24[(size_t)row * 512 + j * 64 + lane];
      acc += v.x + v.y + v.z + v.w;
    }
    for (int off = 32; off > 0; off >>= 1) acc += __shfl_down(acc, off, 64);
    if (lane == 0) w2s[row] = acc;
    return;
  }
  // ---- b2s: 8 experts, 32 lanes each ----
  {
    int e = tid >> 5, l32 = tid & 31;
    float acc = 0.f;
    for (int j = 0; j < 64; ++j) acc += b2[e * 2048 + j * 32 + l32];
    for (int off = 16; off > 0; off >>= 1) acc += __shfl_down(acc, off, 32);
    if (l32 == 0) b2s[e] = acc;
  }
}

// ---------------- GEMM1 (global_load_lds builtin staging) + bias + relu + w2s-dot epilogue ----------------
__global__ __launch_bounds__(256) void gemm_kernel(const f16* __restrict__ A16,
                                                   const f16* __restrict__ W1T,
                                                   const float* __restrict__ b1,
                                                   const float* __restrict__ w2s,
                                                   float* __restrict__ zacc) {
  __shared__ __align__(16) f16 As[128 * 32];
  __shared__ __align__(16) f16 Bs[128 * 32];
  int tid = threadIdx.x;
  int wid = tid >> 6, lane = tid & 63;
  // 4x4 supertile swizzle over 1-D grid for L2 locality
  int bid = blockIdx.x;
  int e = bid >> 8;
  int r = bid & 255;
  int st = r >> 4, wi = r & 15;
  int cT = (st >> 2) * 4 + (wi >> 2);
  int hT = (st & 3) * 4 + (wi & 3);
  int c0 = cT * 128, h0 = hT * 128;
  const f16* Abase = A16 + ((size_t)e * CAP + c0) * DDIM;
  const f16* Bbase = W1T + ((size_t)e * HDIM + h0) * DDIM;
  f32x4 acc[4][4];
#pragma unroll
  for (int i = 0; i < 4; ++i)
#pragma unroll
    for (int j = 0; j < 4; ++j) acc[i][j] = (f32x4){0.f, 0.f, 0.f, 0.f};
  int wm = (wid >> 1) * 64, wn = (wid & 1) * 64;
  int quad = lane >> 4, l15 = lane & 15;

  // DMA staging: wave wid owns rows [wid*32, wid*32+32) of both 128x32 tiles.
  // One global_load_lds_dwordx4 covers 16 rows: lane i loads row i/4, col (i%4)*8 f16,
  // and HW deposits at lds_base + i*16 -> row-major contiguous. 2 instrs per tile per wave.
  const f16* Aln = Abase + (size_t)(wid * 32 + (lane >> 2)) * DDIM + (lane & 3) * 8;
  const f16* Bln = Bbase + (size_t)(wid * 32 + (lane >> 2)) * DDIM + (lane & 3) * 8;
  f16* ldsA0 = &As[wid * 1024];        // wid*32 rows * 32 f16
  f16* ldsA1 = &As[wid * 1024 + 512];  // +16 rows
  f16* ldsB0 = &Bs[wid * 1024];
  f16* ldsB1 = &Bs[wid * 1024 + 512];

  for (int k0 = 0; k0 < DDIM; k0 += 32) {
    __syncthreads();  // previous tile fully consumed
    __builtin_amdgcn_global_load_lds((gas_ptr)(Aln + k0), (las_ptr)ldsA0, 16, 0, 0);
    __builtin_amdgcn_global_load_lds((gas_ptr)(Aln + k0 + 16 * DDIM), (las_ptr)ldsA1, 16, 0, 0);
    __builtin_amdgcn_global_load_lds((gas_ptr)(Bln + k0), (las_ptr)ldsB0, 16, 0, 0);
    __builtin_amdgcn_global_load_lds((gas_ptr)(Bln + k0 + 16 * DDIM), (las_ptr)ldsB1, 16, 0, 0);
    __syncthreads();  // compiler drains vmcnt(0) before barrier: DMA data visible
    f16x8 af[4], bfr[4];
#pragma unroll
    for (int mt = 0; mt < 4; ++mt)
      af[mt] = *(const f16x8*)&As[(wm + mt * 16 + l15) * 32 + quad * 8];
#pragma unroll
    for (int nt = 0; nt < 4; ++nt)
      bfr[nt] = *(const f16x8*)&Bs[(wn + nt * 16 + l15) * 32 + quad * 8];
#pragma unroll
    for (int mt = 0; mt < 4; ++mt)
#pragma unroll
      for (int nt = 0; nt < 4; ++nt)
        acc[mt][nt] = __builtin_amdgcn_mfma_f32_16x16x32_f16(af[mt], bfr[nt], acc[mt][nt], 0, 0, 0);
  }
  // epilogue: rowsum over h of relu(acc + b1) * w2s
  float b1v[4], wsv[4];
#pragma unroll
  for (int nt = 0; nt < 4; ++nt) {
    int h = h0 + wn + nt * 16 + l15;
    b1v[nt] = b1[e * HDIM + h];
    wsv[nt] = w2s[e * HDIM + h];
  }
#pragma unroll
  for (int mt = 0; mt < 4; ++mt) {
    float pr[4];
#pragma unroll
    for (int rr = 0; rr < 4; ++rr) {
      float t = 0.f;
#pragma unroll
      for (int nt = 0; nt < 4; ++nt) {
        float v = acc[mt][nt][rr] + b1v[nt];
        t += (v > 0.f ? v : 0.f) * wsv[nt];
      }
      pr[rr] = t;
    }
#pragma unroll
    for (int rr = 0; rr < 4; ++rr)
#pragma unroll
      for (int off = 1; off < 16; off <<= 1) pr[rr] += __shfl_xor(pr[rr], off, 64);
    if (l15 == 0) {
      int m = c0 + wm + mt * 16 + quad * 4;
#pragma unroll
      for (int rr = 0; rr < 4; ++rr) atomicAdd(&zacc[e * CAP + m + rr], pr[rr]);
    }
  }
}

// ---------------- fused combine + per-batch-row log_softmax ----------------
__global__ __launch_bounds__(256) void tail_kernel(const int* __restrict__ eid,
                                                   const int* __restrict__ locb,
                                                   const float* __restrict__ wts,
                                                   const float* __restrict__ zacc,
                                                   const float* __restrict__ b2s,
                                                   float* __restrict__ out) {
  __shared__ float red[4];
  int b = blockIdx.x, tid = threadIdx.x;
  int wid = tid >> 6, lane = tid & 63;
  float v[8];
  float mx = -1e30f;
#pragma unroll
  for (int i = 0; i < 8; ++i) {
    int s = b * TT + i * 256 + tid;
    float zz = 0.f;
#pragma unroll
    for (int k = 0; k < 2; ++k) {
      int e = eid[2 * s + k], loc = locb[2 * s + k];
      if (loc < CAP) zz += wts[2 * s + k] * (zacc[e * CAP + loc] + b2s[e]);
    }
    v[i] = zz;
    mx = fmaxf(mx, zz);
  }
  for (int off = 32; off > 0; off >>= 1) mx = fmaxf(mx, __shfl_xor(mx, off, 64));
  if (lane == 0) red[wid] = mx;
  __syncthreads();
  mx = fmaxf(fmaxf(red[0], red[1]), fmaxf(red[2], red[3]));
  float sum = 0.f;
#pragma unroll
  for (int i = 0; i < 8; ++i) sum += expf(v[i] - mx);
  for (int off = 32; off > 0; off >>= 1) sum += __shfl_xor(sum, off, 64);
  __syncthreads();
  if (lane == 0) red[wid] = sum;
  __syncthreads();
  sum = red[0] + red[1] + red[2] + red[3];
  float lse = mx + logf(sum);
#pragma unroll
  for (int i = 0; i < 8; ++i) out[b * TT + i * 256 + tid] = v[i] - lse;
}

extern "C" void kernel_launch(void* const* d_in, const int* in_sizes, int n_in,
                              void* d_out, int out_size, void* d_ws, size_t ws_size,
                              hipStream_t stream) {
  const float* x  = (const float*)d_in[0];
  const float* wg = (const float*)d_in[1];
  const float* w1 = (const float*)d_in[2];
  const float* b1 = (const float*)d_in[3];
  const float* w2 = (const float*)d_in[4];
  const float* b2 = (const float*)d_in[5];
  float* out = (float*)d_out;

  char* ws = (char*)d_ws;
  size_t off = 0;
  auto alloc = [&](size_t bytes) -> char* {
    char* p = ws + off;
    off += (bytes + 255) & ~(size_t)255;
    return p;
  };
  f16* A16 = (f16*)alloc((size_t)NE * CAP * DDIM * 2);
  f16* W1T = (f16*)alloc((size_t)NE * HDIM * DDIM * 2);
  float* w2s = (float*)alloc((size_t)NE * HDIM * 4);
  float* b2s = (float*)alloc(NE * 4);
  int* eid = (int*)alloc((size_t)S_TOK * 2 * 4);
  float* wts = (float*)alloc((size_t)S_TOK * 2 * 4);
  int* locb = (int*)alloc((size_t)S_TOK * 2 * 4);
  int* slot_token = (int*)alloc((size_t)NE * CAP * 4);
  float* zacc = (float*)alloc((size_t)NE * CAP * 4);
  if (off > ws_size) return;  // workspace too small: fail loudly via wrong output

  gating_kernel<<<S_TOK / 4, 256, 0, stream>>>(x, wg, eid, wts, slot_token, zacc);
  scan_kernel<<<1, 256, 0, stream>>>(eid, locb, slot_token);
  prep_kernel<<<ABUILD_BASE + NE * CAP, 256, 0, stream>>>(w1, w2, b2, x, slot_token,
                                                          W1T, w2s, b2s, A16);
  gemm_kernel<<<NE * 256, 256, 0, stream>>>(A16, W1T, b1, w2s, zacc);
  tail_kernel<<<NBATCH, 256, 0, stream>>>(eid, locb, wts, zacc, b2s, out);
}